// Round 2
// baseline (7657.038 us; speedup 1.0000x reference)
//
#include <hip/hip_runtime.h>
#include <hip/hip_bf16.h>

typedef unsigned short u16;
typedef unsigned long long u64;
typedef __attribute__((ext_vector_type(8))) short short8;
typedef __attribute__((ext_vector_type(4))) float f32x4;

#define AGENT __HIP_MEMORY_SCOPE_AGENT

__device__ __forceinline__ u16 f2bf(float f) {
  unsigned u = __float_as_uint(f);
  u += 0x7FFFu + ((u >> 16) & 1u);
  return (u16)(u >> 16);
}
__device__ __forceinline__ float bf2f(u16 b) {
  return __uint_as_float(((unsigned)b) << 16);
}

// f32 -> bf16 convert (4 elems/thread)
__global__ void cvt_kernel(const float* __restrict__ in, u16* __restrict__ out, int n) {
  int i = (blockIdx.x * blockDim.x + threadIdx.x) * 4;
  if (i < n) {
    f32x4 v = *(const f32x4*)(in + i);
    out[i + 0] = f2bf(v[0]);
    out[i + 1] = f2bf(v[1]);
    out[i + 2] = f2bf(v[2]);
    out[i + 3] = f2bf(v[3]);
  }
}

// ---------------------------------------------------------------------------
// Tiled bf16 MFMA GEMM:  C[M][N] = A[M][K] * B[N][K]^T + bias[N]
// BM=BN=128, BK=128, block=512 (8 waves), static LDS 64KB, XOR-swizzled chunks.
// ---------------------------------------------------------------------------
template <bool A_F32, bool OUT_F32>
__global__ __launch_bounds__(512, 1) void gemm_kernel(
    const void* __restrict__ Ag, const u16* __restrict__ Bg,
    const float* __restrict__ bias, void* __restrict__ Cg,
    int M, int N, int K) {
  __shared__ __align__(16) u16 As[128 * 128];
  __shared__ __align__(16) u16 Bs[128 * 128];
  const int tid = threadIdx.x;
  const int lane = tid & 63, wave = tid >> 6;
  const int wm = wave & 1, wn = wave >> 1;
  const int m0 = blockIdx.x * 128, n0 = blockIdx.y * 128;

  f32x4 acc[4][2];
#pragma unroll
  for (int i = 0; i < 4; ++i) {
    acc[i][0] = (f32x4){0.f, 0.f, 0.f, 0.f};
    acc[i][1] = (f32x4){0.f, 0.f, 0.f, 0.f};
  }

  const int nk = K >> 7;
  for (int ks = 0; ks < nk; ++ks) {
    for (int i = tid; i < 128 * 16; i += 512) {
      int r = i >> 4, c = i & 15;
      int sw = c ^ (r & 7);
      short8 v;
      if (A_F32) {
        const float* ap = (const float*)Ag + (size_t)(m0 + r) * K + ks * 128 + c * 8;
#pragma unroll
        for (int e = 0; e < 8; ++e) v[e] = (short)f2bf(ap[e]);
      } else {
        v = *(const short8*)((const u16*)Ag + (size_t)(m0 + r) * K + ks * 128 + c * 8);
      }
      *(short8*)(As + (r * 16 + sw) * 8) = v;
    }
    for (int i = tid; i < 128 * 16; i += 512) {
      int r = i >> 4, c = i & 15;
      int sw = c ^ (r & 7);
      *(short8*)(Bs + (r * 16 + sw) * 8) =
          *(const short8*)(Bg + (size_t)(n0 + r) * K + ks * 128 + c * 8);
    }
    __syncthreads();
#pragma unroll
    for (int kb = 0; kb < 4; ++kb) {
      const int cq = kb * 4 + (lane >> 4);
      short8 bfr[2];
#pragma unroll
      for (int j = 0; j < 2; ++j) {
        int rr = wn * 32 + j * 16 + (lane & 15);
        bfr[j] = *(const short8*)(Bs + (rr * 16 + (cq ^ (rr & 7))) * 8);
      }
#pragma unroll
      for (int i2 = 0; i2 < 4; ++i2) {
        int rr = wm * 64 + i2 * 16 + (lane & 15);
        short8 af = *(const short8*)(As + (rr * 16 + (cq ^ (rr & 7))) * 8);
        acc[i2][0] = __builtin_amdgcn_mfma_f32_16x16x32_bf16(af, bfr[0], acc[i2][0], 0, 0, 0);
        acc[i2][1] = __builtin_amdgcn_mfma_f32_16x16x32_bf16(af, bfr[1], acc[i2][1], 0, 0, 0);
      }
    }
    __syncthreads();
  }
#pragma unroll
  for (int i2 = 0; i2 < 4; ++i2) {
#pragma unroll
    for (int j = 0; j < 2; ++j) {
      int ncol = n0 + wn * 32 + j * 16 + (lane & 15);
      float bv = bias[ncol];
#pragma unroll
      for (int r2 = 0; r2 < 4; ++r2) {
        int mrow = m0 + wm * 64 + i2 * 16 + ((lane >> 4) << 2) + r2;
        float v = acc[i2][j][r2] + bv;
        if (OUT_F32)
          ((float*)Cg)[(size_t)mrow * N + ncol] = v;
        else
          ((u16*)Cg)[(size_t)mrow * N + ncol] = f2bf(v);
      }
    }
  }
}

// ---------------------------------------------------------------------------
// Persistent GRU recurrence, latency-optimized:
//  - h state exchanged via RELAXED agent-scope atomics (sc-bit direct-to-L3,
//    no buffer_inv / buffer_wbl2 cache maintenance in the loop)
//  - w_hh hi+lo fully register-resident (no LDS reads in the step GEMM)
//  - 4 independent MFMA accumulator chains (dep chain 32 -> 8)
//  - wx prefetched into registers one step ahead by waves 6-7
// ---------------------------------------------------------------------------
#define T_STEPS 1024

__global__ __launch_bounds__(512, 1) void gru_kernel(
    const float* __restrict__ w_hh, const float* __restrict__ b_hh,
    const u16* __restrict__ wx, u16* __restrict__ hs,
    unsigned* __restrict__ flags) {
  __shared__ __align__(16) u16 whi_lds[3 * 16 * 64 * 8];  // 48KB staging (dead after init)
  __shared__ float whb[32 * 48];
  __shared__ float wxb[32 * 48];
  __shared__ float hold[512];
  __shared__ float bsl[48];

  const int tid = threadIdx.x;
  const int wg = blockIdx.x;
  const int j0 = wg * 16;
  const int lane = tid & 63, wave = tid >> 6;

  // ---- init: W hi -> LDS frag order; b_hh slice; h state = 0
  for (int i = tid; i < 48 * 512; i += 512) {
    int rr = i >> 9, k = i & 511;
    int ngi = rr >> 4, jj = rr & 15;
    float w = w_hh[(size_t)(ngi * 512 + j0 + jj) * 512 + k];
    int idx = (((ngi * 16 + (k >> 5)) * 64) + ((k & 31) >> 3) * 16 + jj) * 8 + (k & 7);
    whi_lds[idx] = f2bf(w);
  }
  if (tid < 48) bsl[tid] = b_hh[(tid >> 4) * 512 + j0 + (tid & 15)];
  hold[tid] = 0.f;
  __syncthreads();

  const int mt = wave & 1, ng = wave >> 1;  // GEMM role for waves 0..5
  short8 whreg[16], wlo[16];
  if (wave < 6) {
    const int grow = ng * 512 + j0 + (lane & 15);
    const int kofs = (lane >> 4) << 3;
#pragma unroll
    for (int kb = 0; kb < 16; ++kb) {
      whreg[kb] = *(const short8*)(whi_lds + ((ng * 16 + kb) * 64 + lane) * 8);
      const float* wp = w_hh + (size_t)grow * 512 + kb * 32 + kofs;
      short8 v;
#pragma unroll
      for (int e = 0; e < 8; ++e) {
        float w = wp[e];
        v[e] = (short)f2bf(w - bf2f(f2bf(w)));
      }
      wlo[kb] = v;
    }
  }

  // wx prefetch registers (waves 6,7): slice for t=0
  u16 wreg[12];
  const int lt = tid - 384;
  if (wave >= 6) {
#pragma unroll
    for (int u = 0; u < 12; ++u) {
      int i = lt + u * 128;
      int seq = i / 48, c = i - seq * 48;
      int g = (c >> 4) * 512 + j0 + (c & 15);
      wreg[u] = wx[(size_t)(seq * T_STEPS + 0) * 1536 + g];
    }
  }

  const int arow = mt * 16 + (lane & 15);  // sequence index for A frag
  const int acol = (lane >> 4) << 3;

  for (int t = 0; t < T_STEPS; ++t) {
    if (wave < 6) {
      f32x4 acc;
      if (t > 0) {
        const u16* hb = hs + ((size_t)(arow * T_STEPS + (t - 1)) << 9) + acol;
        u64 hv[32];
#pragma unroll
        for (int kb = 0; kb < 16; ++kb) {
          hv[2 * kb] = __hip_atomic_load((const u64*)(hb + kb * 32),
                                         __ATOMIC_RELAXED, AGENT);
          hv[2 * kb + 1] = __hip_atomic_load((const u64*)(hb + kb * 32 + 4),
                                             __ATOMIC_RELAXED, AGENT);
        }
        f32x4 a0 = (f32x4){0.f, 0.f, 0.f, 0.f}, a1 = a0, a2 = a0, a3 = a0;
#pragma unroll
        for (int kb = 0; kb < 16; ++kb) {
          short8 af;
          ((u64*)&af)[0] = hv[2 * kb];
          ((u64*)&af)[1] = hv[2 * kb + 1];
          if (kb & 1) {
            a1 = __builtin_amdgcn_mfma_f32_16x16x32_bf16(af, whreg[kb], a1, 0, 0, 0);
            a3 = __builtin_amdgcn_mfma_f32_16x16x32_bf16(af, wlo[kb], a3, 0, 0, 0);
          } else {
            a0 = __builtin_amdgcn_mfma_f32_16x16x32_bf16(af, whreg[kb], a0, 0, 0, 0);
            a2 = __builtin_amdgcn_mfma_f32_16x16x32_bf16(af, wlo[kb], a2, 0, 0, 0);
          }
        }
        acc = (a0 + a1) + (a2 + a3);
      } else {
        acc = (f32x4){0.f, 0.f, 0.f, 0.f};
      }
#pragma unroll
      for (int r = 0; r < 4; ++r)
        whb[(mt * 16 + ((lane >> 4) << 2) + r) * 48 + ng * 16 + (lane & 15)] = acc[r];
    } else {
      // publish current wx regs to LDS, then prefetch next step into regs
#pragma unroll
      for (int u = 0; u < 12; ++u) wxb[lt + u * 128] = bf2f(wreg[u]);
      int tp = (t + 1 < T_STEPS) ? t + 1 : t;
#pragma unroll
      for (int u = 0; u < 12; ++u) {
        int i = lt + u * 128;
        int seq = i / 48, c = i - seq * 48;
        int g = (c >> 4) * 512 + j0 + (c & 15);
        wreg[u] = wx[(size_t)(seq * T_STEPS + tp) * 1536 + g];
      }
    }
    __syncthreads();

    // gates: one (seq, j) per thread
    {
      const int seq = tid >> 4, jj = tid & 15;
      const float* wh = whb + seq * 48;
      const float* wxr = wxb + seq * 48;
      float pr = wxr[jj] + wh[jj] + bsl[jj];
      float pz = wxr[16 + jj] + wh[16 + jj] + bsl[16 + jj];
      float wn_ = wh[32 + jj] + bsl[32 + jj];
      float r = __builtin_amdgcn_rcpf(1.f + __expf(-pr));
      float z = __builtin_amdgcn_rcpf(1.f + __expf(-pz));
      float x2 = wxr[32 + jj] + r * wn_;
      float nn = 1.f - 2.f * __builtin_amdgcn_rcpf(__expf(2.f * x2) + 1.f);
      float hv2 = (1.f - z) * nn + z * hold[tid];
      hold[tid] = hv2;
      __hip_atomic_store(hs + ((size_t)(seq * T_STEPS + t) << 9) + j0 + jj,
                         f2bf(hv2), __ATOMIC_RELAXED, AGENT);
    }
    __syncthreads();  // emits s_waitcnt vmcnt(0): all h stores visible at L3

    if (tid == 0)
      __hip_atomic_store(&flags[wg], (unsigned)(t + 1), __ATOMIC_RELEASE, AGENT);
    if (tid < 32) {
      while (__hip_atomic_load(&flags[tid], __ATOMIC_RELAXED, AGENT) <
             (unsigned)(t + 1)) {
      }
    }
    __syncthreads();
  }
}

// ---------------------------------------------------------------------------
extern "C" void kernel_launch(void* const* d_in, const int* in_sizes, int n_in,
                              void* d_out, int out_size, void* d_ws, size_t ws_size,
                              hipStream_t stream) {
  const float* src = (const float*)d_in[0];   // [32,1024,256]
  const float* w_ih = (const float*)d_in[1];  // [1536,256]
  const float* w_hh = (const float*)d_in[2];  // [1536,512]
  const float* b_ih = (const float*)d_in[3];  // [1536]
  const float* b_hh = (const float*)d_in[4];  // [1536]
  const float* regw = (const float*)d_in[5];  // [256,512]
  const float* regb = (const float*)d_in[6];  // [256]

  char* ws = (char*)d_ws;
  u16* wx = (u16*)(ws);                          // 32768x1536 bf16 = 100663296 B
  u16* hs = (u16*)(ws + 100663296LL);            // 32768x512 bf16 = 33554432 B
  u16* wihb = (u16*)(ws + 134217728LL);          // 1536x256 bf16
  u16* rwb = (u16*)(ws + 135004160LL);           // 256x512 bf16
  unsigned* flags = (unsigned*)(ws + 135266304LL);

  hipMemsetAsync(flags, 0, 256, stream);
  cvt_kernel<<<384, 256, 0, stream>>>(w_ih, wihb, 393216);
  cvt_kernel<<<128, 256, 0, stream>>>(regw, rwb, 131072);

  {  // wx = src @ w_ih^T + b_ih   (bf16 out)
    dim3 g(256, 12);
    gemm_kernel<true, false><<<g, 512, 0, stream>>>((const void*)src, wihb, b_ih,
                                                    (void*)wx, 32768, 1536, 256);
  }
  gru_kernel<<<32, 512, 0, stream>>>(w_hh, b_hh, wx, hs, flags);
  {  // out = hs @ reg_w^T + reg_b  (f32 out)
    dim3 g(256, 2);
    gemm_kernel<false, true><<<g, 512, 0, stream>>>((const void*)hs, rwb, regb,
                                                    d_out, 32768, 256, 512);
  }
}

// Round 4
// 3415.710 us; speedup vs baseline: 2.2417x; 2.2417x over previous
//
#include <hip/hip_runtime.h>
#include <hip/hip_bf16.h>

typedef unsigned short u16;
typedef unsigned int u32;
typedef __attribute__((ext_vector_type(8))) short short8;
typedef __attribute__((ext_vector_type(4))) float f32x4;
typedef __attribute__((ext_vector_type(2))) float f32x2;
typedef __attribute__((ext_vector_type(8))) _Float16 half8;

__device__ __forceinline__ u16 f2h(float f) {
  _Float16 h = (_Float16)f;
  u16 r;
  __builtin_memcpy(&r, &h, 2);
  return r;
}
__device__ __forceinline__ float h2f(u16 b) {
  _Float16 h;
  __builtin_memcpy(&h, &b, 2);
  return (float)h;
}
__device__ __forceinline__ half8 as_h8(short8 s) {
  half8 h;
  __builtin_memcpy(&h, &s, 16);
  return h;
}

// --- device-coherent (LLC-served, L1/L2-bypass) access helpers ------------
__device__ __forceinline__ short8 ldg_cc(const u16* p) {
  short8 r;
  asm volatile("global_load_dwordx4 %0, %1, off sc0 sc1" : "=v"(r) : "v"(p) : "memory");
  return r;
}
__device__ __forceinline__ u32 ld_flag(const u32* p) {
  u32 r;
  asm volatile("global_load_dword %0, %1, off sc0 sc1\n\ts_waitcnt vmcnt(0)"
               : "=v"(r) : "v"(p) : "memory");
  return r;
}
__device__ __forceinline__ void stg_cc(u16* p, u32 v) {
  asm volatile("global_store_dword %0, %1, off sc0 sc1" :: "v"(p), "v"(v) : "memory");
}
__device__ __forceinline__ void st_flag(u32* p, u32 v) {
  asm volatile("global_store_dword %0, %1, off sc0 sc1" :: "v"(p), "v"(v) : "memory");
}

// f32 -> f16 convert (4 elems/thread)
__global__ void cvt16(const float* __restrict__ in, u16* __restrict__ out, int n) {
  int i = (blockIdx.x * blockDim.x + threadIdx.x) * 4;
  if (i < n) {
    f32x4 v = *(const f32x4*)(in + i);
    out[i + 0] = f2h(v[0]);
    out[i + 1] = f2h(v[1]);
    out[i + 2] = f2h(v[2]);
    out[i + 3] = f2h(v[3]);
  }
}

// ---------------------------------------------------------------------------
// Tiled f16 MFMA GEMM:  C[M][N] = A[M][K] * B[N][K]^T + bias[N]
// BM=BN=128, BK=128, block=512. REMAP: store row m -> (m&1023)*32+(m>>10)
// ---------------------------------------------------------------------------
template <bool A_F32, bool OUT_F32, bool REMAP>
__global__ __launch_bounds__(512, 1) void gemm_kernel(
    const void* __restrict__ Ag, const u16* __restrict__ Bg,
    const float* __restrict__ bias, void* __restrict__ Cg,
    int M, int N, int K) {
  __shared__ __align__(16) u16 As[128 * 128];
  __shared__ __align__(16) u16 Bs[128 * 128];
  const int tid = threadIdx.x;
  const int lane = tid & 63, wave = tid >> 6;
  const int wm = wave & 1, wn = wave >> 1;
  const int m0 = blockIdx.x * 128, n0 = blockIdx.y * 128;

  f32x4 acc[4][2];
#pragma unroll
  for (int i = 0; i < 4; ++i) {
    acc[i][0] = (f32x4){0.f, 0.f, 0.f, 0.f};
    acc[i][1] = (f32x4){0.f, 0.f, 0.f, 0.f};
  }

  const int nk = K >> 7;
  for (int ks = 0; ks < nk; ++ks) {
    for (int i = tid; i < 128 * 16; i += 512) {
      int r = i >> 4, c = i & 15;
      int sw = c ^ (r & 7);
      short8 v;
      if (A_F32) {
        const float* ap = (const float*)Ag + (size_t)(m0 + r) * K + ks * 128 + c * 8;
#pragma unroll
        for (int e = 0; e < 8; ++e) v[e] = (short)f2h(ap[e]);
      } else {
        v = *(const short8*)((const u16*)Ag + (size_t)(m0 + r) * K + ks * 128 + c * 8);
      }
      *(short8*)(As + (r * 16 + sw) * 8) = v;
    }
    for (int i = tid; i < 128 * 16; i += 512) {
      int r = i >> 4, c = i & 15;
      int sw = c ^ (r & 7);
      *(short8*)(Bs + (r * 16 + sw) * 8) =
          *(const short8*)(Bg + (size_t)(n0 + r) * K + ks * 128 + c * 8);
    }
    __syncthreads();
#pragma unroll
    for (int kb = 0; kb < 4; ++kb) {
      const int cq = kb * 4 + (lane >> 4);
      short8 bfr[2];
#pragma unroll
      for (int j = 0; j < 2; ++j) {
        int rr = wn * 32 + j * 16 + (lane & 15);
        bfr[j] = *(const short8*)(Bs + (rr * 16 + (cq ^ (rr & 7))) * 8);
      }
#pragma unroll
      for (int i2 = 0; i2 < 4; ++i2) {
        int rr = wm * 64 + i2 * 16 + (lane & 15);
        short8 af = *(const short8*)(As + (rr * 16 + (cq ^ (rr & 7))) * 8);
        acc[i2][0] = __builtin_amdgcn_mfma_f32_16x16x32_f16(as_h8(af), as_h8(bfr[0]),
                                                            acc[i2][0], 0, 0, 0);
        acc[i2][1] = __builtin_amdgcn_mfma_f32_16x16x32_f16(as_h8(af), as_h8(bfr[1]),
                                                            acc[i2][1], 0, 0, 0);
      }
    }
    __syncthreads();
  }
#pragma unroll
  for (int i2 = 0; i2 < 4; ++i2) {
#pragma unroll
    for (int j = 0; j < 2; ++j) {
      int ncol = n0 + wn * 32 + j * 16 + (lane & 15);
      float bv = bias[ncol];
#pragma unroll
      for (int r2 = 0; r2 < 4; ++r2) {
        int mrow = m0 + wm * 64 + i2 * 16 + ((lane >> 4) << 2) + r2;
        size_t orow = REMAP ? ((size_t)(mrow & 1023) * 32 + (mrow >> 10)) : (size_t)mrow;
        float v = acc[i2][j][r2] + bv;
        if (OUT_F32)
          ((float*)Cg)[orow * N + ncol] = v;
        else
          ((u16*)Cg)[orow * N + ncol] = f2h(v);
      }
    }
  }
}

// ---------------------------------------------------------------------------
// Persistent GRU recurrence, 16 WGs x 512 thr (no placement assumptions):
//  - h exchanged in MFMA-frag layout via sc0 sc1 (LLC-coherent, NO cache
//    maintenance instructions anywhere in the loop)
//  - consumers load frags straight to registers (16 pipelined dwordx4/wave)
//  - relaxed flag store after explicit vmcnt(0)+barrier drain; per-wave polls
//  - f16 weights register-resident (wf[2][16] = 128 VGPR)
// ---------------------------------------------------------------------------
#define TS 1024

__global__ __launch_bounds__(512, 1) void gru_kernel(
    const float* __restrict__ w_hh, const float* __restrict__ b_hh,
    const u16* __restrict__ wx, u16* __restrict__ hs,
    u32* __restrict__ flags, u16* __restrict__ hbuf) {
  __shared__ float whb[32][104];             // wh results (padded)
  __shared__ __align__(16) u16 wxb[32][96];  // wx_t slice (f16)
  __shared__ float bsl[96];

  const int tid = threadIdx.x;
  const int wg = blockIdx.x;  // 0..15, owns cols j0..j0+31 (kb == wg)
  const int j0 = wg * 32;
  const int lane = tid & 63, wave = tid >> 6;
  const int mt = wave & 1, ng3 = wave >> 1;  // GEMM role (waves 0..5)

  // ---- weights f16, register-resident
  half8 wf[2][16];
  if (wave < 6) {
#pragma unroll
    for (int tn = 0; tn < 2; ++tn) {
      int l = ng3 * 32 + tn * 16 + (lane & 15);      // local gate row 0..95
      int grow = (l >> 5) * 512 + j0 + (l & 31);     // w_hh row
      int k0 = (lane >> 4) << 3;
#pragma unroll
      for (int kb = 0; kb < 16; ++kb) {
        const float* wp = w_hh + (size_t)grow * 512 + kb * 32 + k0;
        half8 v;
#pragma unroll
        for (int e = 0; e < 8; ++e) v[e] = (_Float16)wp[e];
        wf[tn][kb] = v;
      }
    }
  }
  if (tid < 96) bsl[tid] = b_hh[(tid >> 5) * 512 + j0 + (tid & 31)];

  // ---- wx prefetch for t=0 (waves 6,7)
  short8 wreg[3];
  const int st = tid - 384;
  if (wave >= 6) {
    int seq = st >> 2, ch = st & 3;
#pragma unroll
    for (int g = 0; g < 3; ++g)
      wreg[g] = *(const short8*)(wx + (size_t)(0 * 32 + seq) * 1536 + g * 512 + j0 + ch * 8);
  }

  const int gs = tid >> 4, gjp = tid & 15;  // gate phase: (seq, j-pair)
  float h_old0 = 0.f, h_old1 = 0.f;
  __syncthreads();

  for (int t = 0; t < TS; ++t) {
    // ---- phase B: wh GEMM (waves 0-5) / wx publish+prefetch (waves 6-7)
    if (wave < 6) {
      f32x4 a00 = (f32x4){0.f, 0.f, 0.f, 0.f}, a01 = a00, a10 = a00, a11 = a00;
      if (t > 0) {
        if (lane < 16) {  // wave-local flag poll: h(t-1) ready?
          while (ld_flag(flags + lane) < (u32)t) {}
        }
        const u16* hb = hbuf + ((t - 1) & 1) * 16384;
        short8 f[16];
#pragma unroll
        for (int kb = 0; kb < 16; ++kb)
          f[kb] = ldg_cc(hb + ((kb * 2 + mt) * 64 + lane) * 8);
        asm volatile("s_waitcnt vmcnt(0)" ::: "memory");
        __builtin_amdgcn_sched_barrier(0);
#pragma unroll
        for (int kb = 0; kb < 16; kb += 2) {
          a00 = __builtin_amdgcn_mfma_f32_16x16x32_f16(as_h8(f[kb]), wf[0][kb], a00, 0, 0, 0);
          a10 = __builtin_amdgcn_mfma_f32_16x16x32_f16(as_h8(f[kb]), wf[1][kb], a10, 0, 0, 0);
          a01 = __builtin_amdgcn_mfma_f32_16x16x32_f16(as_h8(f[kb + 1]), wf[0][kb + 1], a01, 0, 0, 0);
          a11 = __builtin_amdgcn_mfma_f32_16x16x32_f16(as_h8(f[kb + 1]), wf[1][kb + 1], a11, 0, 0, 0);
        }
      }
      f32x4 s0 = a00 + a01, s1 = a10 + a11;
      // D frag: row(seq) = mt*16 + (lane>>4)*4 + r, col = ng3*32 + tn*16 + (lane&15)
#pragma unroll
      for (int r = 0; r < 4; ++r) {
        int row = mt * 16 + ((lane >> 4) << 2) + r;
        whb[row][ng3 * 32 + (lane & 15)] = s0[r];
        whb[row][ng3 * 32 + 16 + (lane & 15)] = s1[r];
      }
    } else {
      int seq = st >> 2, ch = st & 3;
#pragma unroll
      for (int g = 0; g < 3; ++g)
        *(short8*)(&wxb[seq][g * 32 + ch * 8]) = wreg[g];
      int tp = (t + 1 < TS) ? t + 1 : t;
#pragma unroll
      for (int g = 0; g < 3; ++g)
        wreg[g] = *(const short8*)(wx + (size_t)(tp * 32 + seq) * 1536 + g * 512 + j0 + ch * 8);
    }
    __syncthreads();  // (1) whb + wxb ready

    // ---- phase C: gates, one (seq, j-pair) per thread
    {
      const float* whr = &whb[gs][0];
      const u16* wxr = &wxb[gs][0];
      const int c = 2 * gjp;
      f32x2 whR = *(const f32x2*)(whr + c);
      f32x2 whZ = *(const f32x2*)(whr + 32 + c);
      f32x2 whN = *(const f32x2*)(whr + 64 + c);
      u32 xR = *(const u32*)(wxr + c);
      u32 xZ = *(const u32*)(wxr + 32 + c);
      u32 xN = *(const u32*)(wxr + 64 + c);
      f32x2 bR = *(const f32x2*)(bsl + c);
      f32x2 bZ = *(const f32x2*)(bsl + 32 + c);
      f32x2 bN = *(const f32x2*)(bsl + 64 + c);
      float hv[2];
#pragma unroll
      for (int e = 0; e < 2; ++e) {
        float pr = h2f((u16)(e ? (xR >> 16) : xR)) + whR[e] + bR[e];
        float pz = h2f((u16)(e ? (xZ >> 16) : xZ)) + whZ[e] + bZ[e];
        float wn_ = whN[e] + bN[e];
        float rr = __builtin_amdgcn_rcpf(1.f + __expf(-pr));
        float zz = __builtin_amdgcn_rcpf(1.f + __expf(-pz));
        float xx = h2f((u16)(e ? (xN >> 16) : xN)) + rr * wn_;
        float nn = 1.f - 2.f * __builtin_amdgcn_rcpf(__expf(2.f * xx) + 1.f);
        float ho = e ? h_old1 : h_old0;
        hv[e] = (1.f - zz) * nn + zz * ho;
      }
      h_old0 = hv[0];
      h_old1 = hv[1];
      u32 pack = (u32)f2h(hv[0]) | ((u32)f2h(hv[1]) << 16);
      // A-frag position for next step: lane=(s&15)|(((j>>3)&3)<<4), e=j&7
      int lane_ = (gs & 15) | ((gjp >> 2) << 4);
      u16* dst = hbuf + (t & 1) * 16384 +
                 (((wg * 2 + (gs >> 4)) * 64 + lane_) << 3) + ((gjp & 3) << 1);
      stg_cc(dst, pack);
      *(u32*)(hs + ((size_t)(gs * TS + t) << 9) + j0 + c) = pack;  // plain (L2)
    }
    asm volatile("s_waitcnt vmcnt(0)" ::: "memory");
    __syncthreads();  // (2) every thread's h stores globally visible

    if (tid == 0) st_flag(flags + wg, (u32)(t + 1));
  }
}

// ---------------------------------------------------------------------------
extern "C" void kernel_launch(void* const* d_in, const int* in_sizes, int n_in,
                              void* d_out, int out_size, void* d_ws, size_t ws_size,
                              hipStream_t stream) {
  const float* src = (const float*)d_in[0];   // [32,1024,256]
  const float* w_ih = (const float*)d_in[1];  // [1536,256]
  const float* w_hh = (const float*)d_in[2];  // [1536,512]
  const float* b_ih = (const float*)d_in[3];  // [1536]
  const float* b_hh = (const float*)d_in[4];  // [1536]
  const float* regw = (const float*)d_in[5];  // [256,512]
  const float* regb = (const float*)d_in[6];  // [256]

  char* ws = (char*)d_ws;
  u16* wx = (u16*)(ws);                  // [t][seq][1536] f16 = 100663296 B
  u16* hs = (u16*)(ws + 100663296LL);    // [seq*1024+t][512] f16 = 33554432 B
  u16* wihb = (u16*)(ws + 134217728LL);  // 1536x256 f16 (dead after wx GEMM)
  u16* rwb = (u16*)(ws + 135004160LL);   // 256x512 f16
  // control block reuses the dead wihb region during gru:
  u32* flags = (u32*)(ws + 134217728LL);       // 64 B (16 flags)
  u16* hbuf = (u16*)(ws + 134217728LL + 4096); // 2 x 32 KB frag double-buffer

  cvt16<<<384, 256, 0, stream>>>(w_ih, wihb, 393216);
  cvt16<<<128, 256, 0, stream>>>(regw, rwb, 131072);

  {  // wx = src @ w_ih^T + b_ih, stored remapped [t][seq][1536] (f16)
    dim3 g(256, 12);
    gemm_kernel<true, false, true><<<g, 512, 0, stream>>>(
        (const void*)src, wihb, b_ih, (void*)wx, 32768, 1536, 256);
  }
  // zero flags AFTER the wx GEMM consumed wihb (region reuse)
  hipMemsetAsync(ws + 134217728LL, 0, 4096, stream);
  gru_kernel<<<16, 512, 0, stream>>>(w_hh, b_hh, wx, hs, flags, hbuf);
  {  // out = hs @ reg_w^T + reg_b  (f32 out)
    dim3 g(256, 2);
    gemm_kernel<false, true, false><<<g, 512, 0, stream>>>(
        (const void*)hs, rwb, regb, d_out, 32768, 256, 512);
  }
}

// Round 5
// 2851.756 us; speedup vs baseline: 2.6850x; 1.1978x over previous
//
#include <hip/hip_runtime.h>
#include <hip/hip_bf16.h>

typedef unsigned short u16;
typedef unsigned int u32;
typedef __attribute__((ext_vector_type(8))) short short8;
typedef __attribute__((ext_vector_type(4))) unsigned int u32x4;
typedef __attribute__((ext_vector_type(4))) float f32x4;
typedef __attribute__((ext_vector_type(2))) float f32x2;
typedef __attribute__((ext_vector_type(8))) _Float16 half8;

__device__ __forceinline__ u16 f2h(float f) {
  _Float16 h = (_Float16)f;
  u16 r;
  __builtin_memcpy(&r, &h, 2);
  return r;
}
__device__ __forceinline__ float h2f(u16 b) {
  _Float16 h;
  __builtin_memcpy(&h, &b, 2);
  return (float)h;
}
__device__ __forceinline__ half8 as_h8(short8 s) {
  half8 h;
  __builtin_memcpy(&h, &s, 16);
  return h;
}
__device__ __forceinline__ half8 as_h8u(u32x4 s) {
  half8 h;
  __builtin_memcpy(&h, &s, 16);
  return h;
}

// --- device-coherent (LLC-served, L1/L2-bypass) access helpers ------------
__device__ __forceinline__ u32x4 ldg_cc4(const u16* p) {
  u32x4 r;
  asm volatile("global_load_dwordx4 %0, %1, off sc0 sc1" : "=v"(r) : "v"(p) : "memory");
  return r;
}
__device__ __forceinline__ void stg_cc(u16* p, u32 v) {
  asm volatile("global_store_dword %0, %1, off sc0 sc1" :: "v"(p), "v"(v) : "memory");
}

// f32 -> f16 convert (4 elems/thread)
__global__ void cvt16(const float* __restrict__ in, u16* __restrict__ out, int n) {
  int i = (blockIdx.x * blockDim.x + threadIdx.x) * 4;
  if (i < n) {
    f32x4 v = *(const f32x4*)(in + i);
    out[i + 0] = f2h(v[0]);
    out[i + 1] = f2h(v[1]);
    out[i + 2] = f2h(v[2]);
    out[i + 3] = f2h(v[3]);
  }
}

// ---------------------------------------------------------------------------
// Tiled f16 MFMA GEMM:  C[M][N] = A[M][K] * B[N][K]^T + bias[N]
// BM=BN=128, BK=128, block=512. REMAP: store row m -> (m&1023)*32+(m>>10)
// ---------------------------------------------------------------------------
template <bool A_F32, bool OUT_F32, bool REMAP>
__global__ __launch_bounds__(512, 1) void gemm_kernel(
    const void* __restrict__ Ag, const u16* __restrict__ Bg,
    const float* __restrict__ bias, void* __restrict__ Cg,
    int M, int N, int K) {
  __shared__ __align__(16) u16 As[128 * 128];
  __shared__ __align__(16) u16 Bs[128 * 128];
  const int tid = threadIdx.x;
  const int lane = tid & 63, wave = tid >> 6;
  const int wm = wave & 1, wn = wave >> 1;
  const int m0 = blockIdx.x * 128, n0 = blockIdx.y * 128;

  f32x4 acc[4][2];
#pragma unroll
  for (int i = 0; i < 4; ++i) {
    acc[i][0] = (f32x4){0.f, 0.f, 0.f, 0.f};
    acc[i][1] = (f32x4){0.f, 0.f, 0.f, 0.f};
  }

  const int nk = K >> 7;
  for (int ks = 0; ks < nk; ++ks) {
    for (int i = tid; i < 128 * 16; i += 512) {
      int r = i >> 4, c = i & 15;
      int sw = c ^ (r & 7);
      short8 v;
      if (A_F32) {
        const float* ap = (const float*)Ag + (size_t)(m0 + r) * K + ks * 128 + c * 8;
#pragma unroll
        for (int e = 0; e < 8; ++e) v[e] = (short)f2h(ap[e]);
      } else {
        v = *(const short8*)((const u16*)Ag + (size_t)(m0 + r) * K + ks * 128 + c * 8);
      }
      *(short8*)(As + (r * 16 + sw) * 8) = v;
    }
    for (int i = tid; i < 128 * 16; i += 512) {
      int r = i >> 4, c = i & 15;
      int sw = c ^ (r & 7);
      *(short8*)(Bs + (r * 16 + sw) * 8) =
          *(const short8*)(Bg + (size_t)(n0 + r) * K + ks * 128 + c * 8);
    }
    __syncthreads();
#pragma unroll
    for (int kb = 0; kb < 4; ++kb) {
      const int cq = kb * 4 + (lane >> 4);
      short8 bfr[2];
#pragma unroll
      for (int j = 0; j < 2; ++j) {
        int rr = wn * 32 + j * 16 + (lane & 15);
        bfr[j] = *(const short8*)(Bs + (rr * 16 + (cq ^ (rr & 7))) * 8);
      }
#pragma unroll
      for (int i2 = 0; i2 < 4; ++i2) {
        int rr = wm * 64 + i2 * 16 + (lane & 15);
        short8 af = *(const short8*)(As + (rr * 16 + (cq ^ (rr & 7))) * 8);
        acc[i2][0] = __builtin_amdgcn_mfma_f32_16x16x32_f16(as_h8(af), as_h8(bfr[0]),
                                                            acc[i2][0], 0, 0, 0);
        acc[i2][1] = __builtin_amdgcn_mfma_f32_16x16x32_f16(as_h8(af), as_h8(bfr[1]),
                                                            acc[i2][1], 0, 0, 0);
      }
    }
    __syncthreads();
  }
#pragma unroll
  for (int i2 = 0; i2 < 4; ++i2) {
#pragma unroll
    for (int j = 0; j < 2; ++j) {
      int ncol = n0 + wn * 32 + j * 16 + (lane & 15);
      float bv = bias[ncol];
#pragma unroll
      for (int r2 = 0; r2 < 4; ++r2) {
        int mrow = m0 + wm * 64 + i2 * 16 + ((lane >> 4) << 2) + r2;
        size_t orow = REMAP ? ((size_t)(mrow & 1023) * 32 + (mrow >> 10)) : (size_t)mrow;
        float v = acc[i2][j][r2] + bv;
        if (OUT_F32)
          ((float*)Cg)[orow * N + ncol] = v;
        else
          ((u16*)Cg)[orow * N + ncol] = f2h(v);
      }
    }
  }
}

// ---------------------------------------------------------------------------
// Persistent GRU recurrence, 16 WGs x 512 thr, SENTINEL-TAG sync:
//  - h exchanged in MFMA-frag layout via sc0 sc1 (LLC-coherent)
//  - 2-bit step tag (t mod 4) embedded in bit0 of each f16 pair; consumers
//    validate-retry on the data itself -> NO flags, NO drains, NO fences
//  - producer side is fire-and-forget; exact values go to hs separately
//  - f16 weights register/AGPR-resident
// ---------------------------------------------------------------------------
#define TS 1024

__global__ __launch_bounds__(512, 1) void gru_kernel(
    const float* __restrict__ w_hh, const float* __restrict__ b_hh,
    const u16* __restrict__ wx, u16* __restrict__ hs,
    u16* __restrict__ hbuf) {
  __shared__ float whb[32][104];             // wh results (padded)
  __shared__ __align__(16) u16 wxb[32][96];  // wx_t slice (f16)
  __shared__ float bsl[96];

  const int tid = threadIdx.x;
  const int wg = blockIdx.x;  // 0..15, owns cols j0..j0+31 (kb == wg)
  const int j0 = wg * 32;
  const int lane = tid & 63, wave = tid >> 6;
  const int mt = wave & 1, ng3 = wave >> 1;  // GEMM role (waves 0..5)

  // ---- weights f16, register-resident
  half8 wf[2][16];
  if (wave < 6) {
#pragma unroll
    for (int tn = 0; tn < 2; ++tn) {
      int l = ng3 * 32 + tn * 16 + (lane & 15);      // local gate row 0..95
      int grow = (l >> 5) * 512 + j0 + (l & 31);     // w_hh row
      int k0 = (lane >> 4) << 3;
#pragma unroll
      for (int kb = 0; kb < 16; ++kb) {
        const float* wp = w_hh + (size_t)grow * 512 + kb * 32 + k0;
        half8 v;
#pragma unroll
        for (int e = 0; e < 8; ++e) v[e] = (_Float16)wp[e];
        wf[tn][kb] = v;
      }
    }
  }
  if (tid < 96) bsl[tid] = b_hh[(tid >> 5) * 512 + j0 + (tid & 31)];

  // ---- wx prefetch for t=0 (waves 6,7)
  short8 wreg[3];
  const int st = tid - 384;
  if (wave >= 6) {
    int seq = st >> 2, ch = st & 3;
#pragma unroll
    for (int g = 0; g < 3; ++g)
      wreg[g] = *(const short8*)(wx + (size_t)(0 * 32 + seq) * 1536 + g * 512 + j0 + ch * 8);
  }

  const int gs = tid >> 4, gjp = tid & 15;  // gate phase: (seq, j-pair)
  float h_old0 = 0.f, h_old1 = 0.f;
  __syncthreads();

  for (int t = 0; t < TS; ++t) {
    // ---- phase B: wh GEMM (waves 0-5) / wx publish+prefetch (waves 6-7)
    if (wave < 6) {
      f32x4 a00 = (f32x4){0.f, 0.f, 0.f, 0.f}, a01 = a00, a10 = a00, a11 = a00;
      if (t > 0) {
        const u16* hb = hbuf + ((t - 1) & 1) * 16384;
        const u32 p = (u32)((t - 1) & 1) | ((u32)(((t - 1) >> 1) & 1) << 16);
        u32x4 f[16];
        // validate-retry: data is fresh iff every dword carries tag (t-1)&3
        for (;;) {
#pragma unroll
          for (int kb = 0; kb < 16; ++kb)
            f[kb] = ldg_cc4(hb + ((kb * 2 + mt) * 64 + lane) * 8);
          asm volatile("s_waitcnt vmcnt(0)" ::: "memory");
          __builtin_amdgcn_sched_barrier(0);
          u32 aOR = 0u, aAND = 0xFFFFFFFFu;
#pragma unroll
          for (int kb = 0; kb < 16; ++kb) {
#pragma unroll
            for (int d = 0; d < 4; ++d) {
              aOR |= f[kb][d];
              aAND &= f[kb][d];
            }
          }
          int ok = ((aOR & 0x00010001u) == p) & ((aAND & 0x00010001u) == p);
          if (__all(ok)) break;
        }
#pragma unroll
        for (int kb = 0; kb < 16; kb += 2) {
          a00 = __builtin_amdgcn_mfma_f32_16x16x32_f16(as_h8u(f[kb]), wf[0][kb], a00, 0, 0, 0);
          a10 = __builtin_amdgcn_mfma_f32_16x16x32_f16(as_h8u(f[kb]), wf[1][kb], a10, 0, 0, 0);
          a01 = __builtin_amdgcn_mfma_f32_16x16x32_f16(as_h8u(f[kb + 1]), wf[0][kb + 1], a01, 0, 0, 0);
          a11 = __builtin_amdgcn_mfma_f32_16x16x32_f16(as_h8u(f[kb + 1]), wf[1][kb + 1], a11, 0, 0, 0);
        }
      }
      f32x4 s0 = a00 + a01, s1 = a10 + a11;
#pragma unroll
      for (int r = 0; r < 4; ++r) {
        int row = mt * 16 + ((lane >> 4) << 2) + r;
        whb[row][ng3 * 32 + (lane & 15)] = s0[r];
        whb[row][ng3 * 32 + 16 + (lane & 15)] = s1[r];
      }
    } else {
      int seq = st >> 2, ch = st & 3;
#pragma unroll
      for (int g = 0; g < 3; ++g)
        *(short8*)(&wxb[seq][g * 32 + ch * 8]) = wreg[g];
      int tp = (t + 1 < TS) ? t + 1 : t;
#pragma unroll
      for (int g = 0; g < 3; ++g)
        wreg[g] = *(const short8*)(wx + (size_t)(tp * 32 + seq) * 1536 + g * 512 + j0 + ch * 8);
    }
    __syncthreads();  // (1) whb + wxb ready

    // ---- phase C: gates, one (seq, j-pair) per thread
    {
      const float* whr = &whb[gs][0];
      const u16* wxr = &wxb[gs][0];
      const int c = 2 * gjp;
      f32x2 whR = *(const f32x2*)(whr + c);
      f32x2 whZ = *(const f32x2*)(whr + 32 + c);
      f32x2 whN = *(const f32x2*)(whr + 64 + c);
      u32 xR = *(const u32*)(wxr + c);
      u32 xZ = *(const u32*)(wxr + 32 + c);
      u32 xN = *(const u32*)(wxr + 64 + c);
      f32x2 bR = *(const f32x2*)(bsl + c);
      f32x2 bZ = *(const f32x2*)(bsl + 32 + c);
      f32x2 bN = *(const f32x2*)(bsl + 64 + c);
      float hv[2];
#pragma unroll
      for (int e = 0; e < 2; ++e) {
        float pr = h2f((u16)(e ? (xR >> 16) : xR)) + whR[e] + bR[e];
        float pz = h2f((u16)(e ? (xZ >> 16) : xZ)) + whZ[e] + bZ[e];
        float wn_ = whN[e] + bN[e];
        float rr = __builtin_amdgcn_rcpf(1.f + __expf(-pr));
        float zz = __builtin_amdgcn_rcpf(1.f + __expf(-pz));
        float xx = h2f((u16)(e ? (xN >> 16) : xN)) + rr * wn_;
        float nn = 1.f - 2.f * __builtin_amdgcn_rcpf(__expf(2.f * xx) + 1.f);
        float ho = e ? h_old1 : h_old0;
        hv[e] = (1.f - zz) * nn + zz * ho;
      }
      h_old0 = hv[0];
      h_old1 = hv[1];
      u32 b0 = (u32)f2h(hv[0]), b1 = (u32)f2h(hv[1]);
      u32 packo = b0 | (b1 << 16);  // exact, for the output path
      u32 packt = (b0 & 0xFFFEu) | (u32)(t & 1) |
                  (((b1 & 0xFFFEu) | (u32)((t >> 1) & 1)) << 16);  // tagged
      int lane_ = (gs & 15) | ((gjp >> 2) << 4);
      u16* dst = hbuf + (t & 1) * 16384 +
                 (((wg * 2 + (gs >> 4)) * 64 + lane_) << 3) + ((gjp & 3) << 1);
      stg_cc(dst, packt);  // fire-and-forget; tag validates freshness
      *(u32*)(hs + ((size_t)(gs * TS + t) << 9) + j0 + c) = packo;
    }
    __syncthreads();  // (2) LDS reuse safety (whb/wxb rewritten next step)
  }
}

// ---------------------------------------------------------------------------
extern "C" void kernel_launch(void* const* d_in, const int* in_sizes, int n_in,
                              void* d_out, int out_size, void* d_ws, size_t ws_size,
                              hipStream_t stream) {
  const float* src = (const float*)d_in[0];   // [32,1024,256]
  const float* w_ih = (const float*)d_in[1];  // [1536,256]
  const float* w_hh = (const float*)d_in[2];  // [1536,512]
  const float* b_ih = (const float*)d_in[3];  // [1536]
  const float* b_hh = (const float*)d_in[4];  // [1536]
  const float* regw = (const float*)d_in[5];  // [256,512]
  const float* regb = (const float*)d_in[6];  // [256]

  char* ws = (char*)d_ws;
  u16* wx = (u16*)(ws);                  // [t][seq][1536] f16 = 100663296 B
  u16* hs = (u16*)(ws + 100663296LL);    // [seq*1024+t][512] f16 = 33554432 B
  u16* wihb = (u16*)(ws + 134217728LL);  // 1536x256 f16 (dead after wx GEMM)
  u16* rwb = (u16*)(ws + 135004160LL);   // 256x512 f16
  // hbuf reuses the dead wihb region during gru:
  u16* hbuf = (u16*)(ws + 134217728LL + 4096);  // 2 x 32 KB frag double-buffer

  cvt16<<<384, 256, 0, stream>>>(w_ih, wihb, 393216);
  cvt16<<<128, 256, 0, stream>>>(regw, rwb, 131072);

  {  // wx = src @ w_ih^T + b_ih, stored remapped [t][seq][1536] (f16)
    dim3 g(256, 12);
    gemm_kernel<true, false, true><<<g, 512, 0, stream>>>(
        (const void*)src, wihb, b_ih, (void*)wx, 32768, 1536, 256);
  }
  // init hbuf to 0xFF AFTER the wx GEMM consumed wihb: tag bits = (1,1),
  // mismatching t=1/t=2 expectations; also kills the 0xAA-poison (tag 0)
  // collision. Runs every launch (graph-capture safe: async on stream).
  hipMemsetAsync(ws + 134217728LL + 4096, 0xFF, 65536, stream);
  gru_kernel<<<16, 512, 0, stream>>>(w_hh, b_hh, wx, hs, hbuf);
  {  // out = hs @ reg_w^T + reg_b  (f32 out)
    dim3 g(256, 2);
    gemm_kernel<false, true, false><<<g, 512, 0, stream>>>(
        (const void*)hs, rwb, regb, d_out, 32768, 256, 512);
  }
}

// Round 6
// 2458.150 us; speedup vs baseline: 3.1150x; 1.1601x over previous
//
#include <hip/hip_runtime.h>
#include <hip/hip_bf16.h>

typedef unsigned short u16;
typedef unsigned int u32;
typedef unsigned long long u64;
typedef __attribute__((ext_vector_type(8))) short short8;
typedef __attribute__((ext_vector_type(4))) unsigned int u32x4;
typedef __attribute__((ext_vector_type(4))) float f32x4;
typedef __attribute__((ext_vector_type(8))) _Float16 half8;

__device__ __forceinline__ u16 f2h(float f) {
  _Float16 h = (_Float16)f;
  u16 r;
  __builtin_memcpy(&r, &h, 2);
  return r;
}
__device__ __forceinline__ float h2f(u16 b) {
  _Float16 h;
  __builtin_memcpy(&h, &b, 2);
  return (float)h;
}
__device__ __forceinline__ half8 as_h8(short8 s) {
  half8 h;
  __builtin_memcpy(&h, &s, 16);
  return h;
}
__device__ __forceinline__ half8 as_h8u(u32x4 s) {
  half8 h;
  __builtin_memcpy(&h, &s, 16);
  return h;
}

// f32 -> f16 convert (4 elems/thread)
__global__ void cvt16(const float* __restrict__ in, u16* __restrict__ out, int n) {
  int i = (blockIdx.x * blockDim.x + threadIdx.x) * 4;
  if (i < n) {
    f32x4 v = *(const f32x4*)(in + i);
    out[i + 0] = f2h(v[0]);
    out[i + 1] = f2h(v[1]);
    out[i + 2] = f2h(v[2]);
    out[i + 3] = f2h(v[3]);
  }
}

// ---------------------------------------------------------------------------
// Tiled f16 MFMA GEMM:  C[M][N] = A[M][K] * B[N][K]^T + bias[N]
// BM=BN=128, BK=128, block=512. REMAP: store row m -> (m&1023)*32+(m>>10)
// ---------------------------------------------------------------------------
template <bool A_F32, bool OUT_F32, bool REMAP>
__global__ __launch_bounds__(512, 1) void gemm_kernel(
    const void* __restrict__ Ag, const u16* __restrict__ Bg,
    const float* __restrict__ bias, void* __restrict__ Cg,
    int M, int N, int K) {
  __shared__ __align__(16) u16 As[128 * 128];
  __shared__ __align__(16) u16 Bs[128 * 128];
  const int tid = threadIdx.x;
  const int lane = tid & 63, wave = tid >> 6;
  const int wm = wave & 1, wn = wave >> 1;
  const int m0 = blockIdx.x * 128, n0 = blockIdx.y * 128;

  f32x4 acc[4][2];
#pragma unroll
  for (int i = 0; i < 4; ++i) {
    acc[i][0] = (f32x4){0.f, 0.f, 0.f, 0.f};
    acc[i][1] = (f32x4){0.f, 0.f, 0.f, 0.f};
  }

  const int nk = K >> 7;
  for (int ks = 0; ks < nk; ++ks) {
    for (int i = tid; i < 128 * 16; i += 512) {
      int r = i >> 4, c = i & 15;
      int sw = c ^ (r & 7);
      short8 v;
      if (A_F32) {
        const float* ap = (const float*)Ag + (size_t)(m0 + r) * K + ks * 128 + c * 8;
#pragma unroll
        for (int e = 0; e < 8; ++e) v[e] = (short)f2h(ap[e]);
      } else {
        v = *(const short8*)((const u16*)Ag + (size_t)(m0 + r) * K + ks * 128 + c * 8);
      }
      *(short8*)(As + (r * 16 + sw) * 8) = v;
    }
    for (int i = tid; i < 128 * 16; i += 512) {
      int r = i >> 4, c = i & 15;
      int sw = c ^ (r & 7);
      *(short8*)(Bs + (r * 16 + sw) * 8) =
          *(const short8*)(Bg + (size_t)(n0 + r) * K + ks * 128 + c * 8);
    }
    __syncthreads();
#pragma unroll
    for (int kb = 0; kb < 4; ++kb) {
      const int cq = kb * 4 + (lane >> 4);
      short8 bfr[2];
#pragma unroll
      for (int j = 0; j < 2; ++j) {
        int rr = wn * 32 + j * 16 + (lane & 15);
        bfr[j] = *(const short8*)(Bs + (rr * 16 + (cq ^ (rr & 7))) * 8);
      }
#pragma unroll
      for (int i2 = 0; i2 < 4; ++i2) {
        int rr = wm * 64 + i2 * 16 + (lane & 15);
        short8 af = *(const short8*)(As + (rr * 16 + (cq ^ (rr & 7))) * 8);
        acc[i2][0] = __builtin_amdgcn_mfma_f32_16x16x32_f16(as_h8(af), as_h8(bfr[0]),
                                                            acc[i2][0], 0, 0, 0);
        acc[i2][1] = __builtin_amdgcn_mfma_f32_16x16x32_f16(as_h8(af), as_h8(bfr[1]),
                                                            acc[i2][1], 0, 0, 0);
      }
    }
    __syncthreads();
  }
#pragma unroll
  for (int i2 = 0; i2 < 4; ++i2) {
#pragma unroll
    for (int j = 0; j < 2; ++j) {
      int ncol = n0 + wn * 32 + j * 16 + (lane & 15);
      float bv = bias[ncol];
#pragma unroll
      for (int r2 = 0; r2 < 4; ++r2) {
        int mrow = m0 + wm * 64 + i2 * 16 + ((lane >> 4) << 2) + r2;
        size_t orow = REMAP ? ((size_t)(mrow & 1023) * 32 + (mrow >> 10)) : (size_t)mrow;
        float v = acc[i2][j][r2] + bv;
        if (OUT_F32)
          ((float*)Cg)[orow * N + ncol] = v;
        else
          ((u16*)Cg)[orow * N + ncol] = f2h(v);
      }
    }
  }
}

// ---------------------------------------------------------------------------
// Persistent GRU recurrence: 64 fully-AUTONOMOUS waves (64 WGs x 64 thr).
// Wave (wgq, mt, jblk) owns output block seqs[mt*16..+16) x cols[wgq*32+jblk*16..+16)
// and computes ALL THREE gates for it (3 n-tiles x 16 kb = 48 MFMAs; weights
// 192 VGPR-resident). Gates are evaluated directly from MFMA accumulators in
// registers -> NO LDS, NO barriers, NO flags anywhere in the loop. h is
// exchanged via sc0 sc1 (LLC-coherent) with 2-bit step tags in f16 bit0;
// consumers validate-retry. Skew bound <2 slots holds per-wave.
// ---------------------------------------------------------------------------
#define TS 1024

__global__ __launch_bounds__(64, 1) void gru_kernel(
    const float* __restrict__ w_hh, const float* __restrict__ b_hh,
    const u16* __restrict__ wx, u16* __restrict__ hs,
    u16* __restrict__ hbuf) {
  const int lane = threadIdx.x & 63;
  const int wgq = blockIdx.x >> 2;        // h-col quad 0..15 (K-block kb)
  const int mt = (blockIdx.x >> 1) & 1;   // seq half
  const int jblk = blockIdx.x & 1;        // 16-col half within the quad
  const int colL = jblk * 16 + (lane & 15);  // col local 0..31
  const int colH = wgq * 32 + colL;          // global h col
  const int k0 = (lane >> 4) << 3;
  const int seqb = mt * 16 + ((lane >> 4) << 2);  // base seq for r=0

  // ---- weights f16, register-resident: 3 gates x 16 k-blocks
  half8 wf[3][16];
#pragma unroll
  for (int g = 0; g < 3; ++g) {
    const float* wrow = w_hh + (size_t)(g * 512 + colH) * 512 + k0;
#pragma unroll
    for (int kb = 0; kb < 16; ++kb) {
      half8 v;
#pragma unroll
      for (int e = 0; e < 8; ++e) v[e] = (_Float16)wrow[kb * 32 + e];
      wf[g][kb] = v;
    }
  }
  const float bR = b_hh[colH], bZ = b_hh[512 + colH], bN = b_hh[1024 + colH];

  // probe voffsets (bytes): consumer A-frag dwordx4 at ((kb*2+mt)*64+lane)*16
  u32 pvoff[16];
#pragma unroll
  for (int kb = 0; kb < 16; ++kb) pvoff[kb] = (u32)(((kb * 2 + mt) * 64 + lane) * 16);
  // store voffset (bytes) for r=0; r adds 16B (lane_c increments by 1)
  const u32 svoff0 =
      (u32)((((wgq * 2 + mt) * 64 +
              (((lane >> 4) << 2) | (((colL >> 3) & 3) << 4))) * 8 + (lane & 7)) * 2);

  // wx(0) prefetch (12 u16 per lane)
  u16 wxr[3][4];
#pragma unroll
  for (int g = 0; g < 3; ++g)
#pragma unroll
    for (int r = 0; r < 4; ++r)
      wxr[g][r] = wx[(size_t)(seqb + r) * 1536 + g * 512 + colH];

  float h_old[4] = {0.f, 0.f, 0.f, 0.f};

  for (int t = 0; t < TS; ++t) {
    f32x4 accS[3];
    if (t > 0) {
      const u64 sb = (u64)(hbuf + ((t - 1) & 1) * 16384);
      const u32 p = (u32)((t - 1) & 1) | ((u32)(((t - 1) >> 1) & 1) << 16);
      u32x4 f[16];
      for (;;) {
#pragma unroll
        for (int kb = 0; kb < 16; ++kb)
          asm volatile("global_load_dwordx4 %0, %1, %2 sc0 sc1"
                       : "=v"(f[kb]) : "v"(pvoff[kb]), "s"(sb) : "memory");
        asm volatile("s_waitcnt vmcnt(0)" ::: "memory");
        __builtin_amdgcn_sched_barrier(0);
        u32 aOR = 0u, aAND = 0xFFFFFFFFu;
#pragma unroll
        for (int kb = 0; kb < 16; ++kb)
#pragma unroll
          for (int d = 0; d < 4; ++d) { aOR |= f[kb][d]; aAND &= f[kb][d]; }
        int ok = ((aOR & 0x00010001u) == p) & ((aAND & 0x00010001u) == p);
        if (__all(ok)) break;
      }
      f32x4 a[3][2];
#pragma unroll
      for (int g = 0; g < 3; ++g) {
        a[g][0] = (f32x4){0.f, 0.f, 0.f, 0.f};
        a[g][1] = (f32x4){0.f, 0.f, 0.f, 0.f};
      }
#pragma unroll
      for (int kb = 0; kb < 16; kb += 2) {
        half8 h0 = as_h8u(f[kb]), h1 = as_h8u(f[kb + 1]);
#pragma unroll
        for (int g = 0; g < 3; ++g) {
          a[g][0] = __builtin_amdgcn_mfma_f32_16x16x32_f16(h0, wf[g][kb], a[g][0], 0, 0, 0);
          a[g][1] = __builtin_amdgcn_mfma_f32_16x16x32_f16(h1, wf[g][kb + 1], a[g][1], 0, 0, 0);
        }
      }
#pragma unroll
      for (int g = 0; g < 3; ++g) accS[g] = a[g][0] + a[g][1];
    } else {
#pragma unroll
      for (int g = 0; g < 3; ++g) accS[g] = (f32x4){0.f, 0.f, 0.f, 0.f};
    }

    // prefetch wx(t+1) (overlaps gate math; drained by next step's vmcnt(0))
    u16 wxn[3][4];
    {
      int tp = (t + 1 < TS) ? t + 1 : t;
#pragma unroll
      for (int g = 0; g < 3; ++g)
#pragma unroll
        for (int r = 0; r < 4; ++r)
          wxn[g][r] = wx[(size_t)(tp * 32 + seqb + r) * 1536 + g * 512 + colH];
    }

    // gates in registers; tagged h store issues per-r ASAP
    const u64 sb2 = (u64)(hbuf + (t & 1) * 16384);
    const u32 tagbit = (colL & 1) ? (u32)((t >> 1) & 1) : (u32)(t & 1);
#pragma unroll
    for (int r = 0; r < 4; ++r) {
      float pr = h2f(wxr[0][r]) + accS[0][r] + bR;
      float pz = h2f(wxr[1][r]) + accS[1][r] + bZ;
      float rr = __builtin_amdgcn_rcpf(1.f + __expf(-pr));
      float zz = __builtin_amdgcn_rcpf(1.f + __expf(-pz));
      float xx = h2f(wxr[2][r]) + rr * (accS[2][r] + bN);
      float nn = 1.f - 2.f * __builtin_amdgcn_rcpf(__expf(2.f * xx) + 1.f);
      float hv = (1.f - zz) * nn + zz * h_old[r];
      h_old[r] = hv;
      u32 hbits = (u32)f2h(hv);
      u32 tv = (hbits & 0xFFFEu) | tagbit;
      asm volatile("global_store_short %0, %1, %2 sc0 sc1"
                   :: "v"(svoff0 + r * 16), "v"(tv), "s"(sb2) : "memory");
      hs[((size_t)((seqb + r) * TS + t) << 9) + colH] = (u16)hbits;  // exact copy
    }
#pragma unroll
    for (int g = 0; g < 3; ++g)
#pragma unroll
      for (int r = 0; r < 4; ++r) wxr[g][r] = wxn[g][r];
  }
}

// ---------------------------------------------------------------------------
extern "C" void kernel_launch(void* const* d_in, const int* in_sizes, int n_in,
                              void* d_out, int out_size, void* d_ws, size_t ws_size,
                              hipStream_t stream) {
  const float* src = (const float*)d_in[0];   // [32,1024,256]
  const float* w_ih = (const float*)d_in[1];  // [1536,256]
  const float* w_hh = (const float*)d_in[2];  // [1536,512]
  const float* b_ih = (const float*)d_in[3];  // [1536]
  const float* b_hh = (const float*)d_in[4];  // [1536]
  const float* regw = (const float*)d_in[5];  // [256,512]
  const float* regb = (const float*)d_in[6];  // [256]

  char* ws = (char*)d_ws;
  u16* wx = (u16*)(ws);                  // [t][seq][1536] f16 = 100663296 B
  u16* hs = (u16*)(ws + 100663296LL);    // [seq*1024+t][512] f16 = 33554432 B
  u16* wihb = (u16*)(ws + 134217728LL);  // 1536x256 f16 (dead after wx GEMM)
  u16* rwb = (u16*)(ws + 135004160LL);   // 256x512 f16
  // hbuf reuses the dead wihb region during gru:
  u16* hbuf = (u16*)(ws + 134217728LL + 4096);  // 2 x 32 KB frag double-buffer

  cvt16<<<384, 256, 0, stream>>>(w_ih, wihb, 393216);
  cvt16<<<128, 256, 0, stream>>>(regw, rwb, 131072);

  {  // wx = src @ w_ih^T + b_ih, stored remapped [t][seq][1536] (f16)
    dim3 g(256, 12);
    gemm_kernel<true, false, true><<<g, 512, 0, stream>>>(
        (const void*)src, wihb, b_ih, (void*)wx, 32768, 1536, 256);
  }
  // init hbuf to 0xFF AFTER the wx GEMM consumed wihb: tag bits (1,1) mismatch
  // t=1/t=2 expectations; also kills the 0xAA-poison (tag 0) collision.
  hipMemsetAsync(ws + 134217728LL + 4096, 0xFF, 65536, stream);
  gru_kernel<<<64, 64, 0, stream>>>(w_hh, b_hh, wx, hs, hbuf);
  {  // out = hs @ reg_w^T + reg_b  (f32 out)
    dim3 g(256, 2);
    gemm_kernel<false, true, false><<<g, 512, 0, stream>>>(
        (const void*)hs, rwb, regb, d_out, 32768, 256, 512);
  }
}

// Round 9
// 2316.013 us; speedup vs baseline: 3.3061x; 1.0614x over previous
//
#include <hip/hip_runtime.h>
#include <hip/hip_bf16.h>

typedef unsigned short u16;
typedef unsigned int u32;
typedef unsigned long long u64;
typedef __attribute__((ext_vector_type(8))) short short8;
typedef __attribute__((ext_vector_type(4))) unsigned int u32x4;
typedef __attribute__((ext_vector_type(4))) float f32x4;
typedef __attribute__((ext_vector_type(8))) _Float16 half8;

__device__ __forceinline__ u16 f2h(float f) {
  _Float16 h = (_Float16)f;
  u16 r;
  __builtin_memcpy(&r, &h, 2);
  return r;
}
__device__ __forceinline__ float h2f(u16 b) {
  _Float16 h;
  __builtin_memcpy(&h, &b, 2);
  return (float)h;
}
__device__ __forceinline__ half8 as_h8(short8 s) {
  half8 h;
  __builtin_memcpy(&h, &s, 16);
  return h;
}
__device__ __forceinline__ half8 as_h8u(u32x4 s) {
  half8 h;
  __builtin_memcpy(&h, &s, 16);
  return h;
}

// f32 -> f16 convert (4 elems/thread)
__global__ void cvt16(const float* __restrict__ in, u16* __restrict__ out, int n) {
  int i = (blockIdx.x * blockDim.x + threadIdx.x) * 4;
  if (i < n) {
    f32x4 v = *(const f32x4*)(in + i);
    out[i + 0] = f2h(v[0]);
    out[i + 1] = f2h(v[1]);
    out[i + 2] = f2h(v[2]);
    out[i + 3] = f2h(v[3]);
  }
}

// ---------------------------------------------------------------------------
// Tiled f16 MFMA GEMM:  C[M][N] = A[M][K] * B[N][K]^T + bias[N]
// BM=BN=128, BK=128, block=512. REMAP: store row m -> (m&1023)*32+(m>>10)
// ---------------------------------------------------------------------------
template <bool A_F32, bool OUT_F32, bool REMAP>
__global__ __launch_bounds__(512, 1) void gemm_kernel(
    const void* __restrict__ Ag, const u16* __restrict__ Bg,
    const float* __restrict__ bias, void* __restrict__ Cg,
    int M, int N, int K) {
  __shared__ __align__(16) u16 As[128 * 128];
  __shared__ __align__(16) u16 Bs[128 * 128];
  const int tid = threadIdx.x;
  const int lane = tid & 63, wave = tid >> 6;
  const int wm = wave & 1, wn = wave >> 1;
  const int m0 = blockIdx.x * 128, n0 = blockIdx.y * 128;

  f32x4 acc[4][2];
#pragma unroll
  for (int i = 0; i < 4; ++i) {
    acc[i][0] = (f32x4){0.f, 0.f, 0.f, 0.f};
    acc[i][1] = (f32x4){0.f, 0.f, 0.f, 0.f};
  }

  const int nk = K >> 7;
  for (int ks = 0; ks < nk; ++ks) {
    for (int i = tid; i < 128 * 16; i += 512) {
      int r = i >> 4, c = i & 15;
      int sw = c ^ (r & 7);
      short8 v;
      if (A_F32) {
        const float* ap = (const float*)Ag + (size_t)(m0 + r) * K + ks * 128 + c * 8;
#pragma unroll
        for (int e = 0; e < 8; ++e) v[e] = (short)f2h(ap[e]);
      } else {
        v = *(const short8*)((const u16*)Ag + (size_t)(m0 + r) * K + ks * 128 + c * 8);
      }
      *(short8*)(As + (r * 16 + sw) * 8) = v;
    }
    for (int i = tid; i < 128 * 16; i += 512) {
      int r = i >> 4, c = i & 15;
      int sw = c ^ (r & 7);
      *(short8*)(Bs + (r * 16 + sw) * 8) =
          *(const short8*)(Bg + (size_t)(n0 + r) * K + ks * 128 + c * 8);
    }
    __syncthreads();
#pragma unroll
    for (int kb = 0; kb < 4; ++kb) {
      const int cq = kb * 4 + (lane >> 4);
      short8 bfr[2];
#pragma unroll
      for (int j = 0; j < 2; ++j) {
        int rr = wn * 32 + j * 16 + (lane & 15);
        bfr[j] = *(const short8*)(Bs + (rr * 16 + (cq ^ (rr & 7))) * 8);
      }
#pragma unroll
      for (int i2 = 0; i2 < 4; ++i2) {
        int rr = wm * 64 + i2 * 16 + (lane & 15);
        short8 af = *(const short8*)(As + (rr * 16 + (cq ^ (rr & 7))) * 8);
        acc[i2][0] = __builtin_amdgcn_mfma_f32_16x16x32_f16(as_h8(af), as_h8(bfr[0]),
                                                            acc[i2][0], 0, 0, 0);
        acc[i2][1] = __builtin_amdgcn_mfma_f32_16x16x32_f16(as_h8(af), as_h8(bfr[1]),
                                                            acc[i2][1], 0, 0, 0);
      }
    }
    __syncthreads();
  }
#pragma unroll
  for (int i2 = 0; i2 < 4; ++i2) {
#pragma unroll
    for (int j = 0; j < 2; ++j) {
      int ncol = n0 + wn * 32 + j * 16 + (lane & 15);
      float bv = bias[ncol];
#pragma unroll
      for (int r2 = 0; r2 < 4; ++r2) {
        int mrow = m0 + wm * 64 + i2 * 16 + ((lane >> 4) << 2) + r2;
        size_t orow = REMAP ? ((size_t)(mrow & 1023) * 32 + (mrow >> 10)) : (size_t)mrow;
        float v = acc[i2][j][r2] + bv;
        if (OUT_F32)
          ((float*)Cg)[orow * N + ncol] = v;
        else
          ((u16*)Cg)[orow * N + ncol] = f2h(v);
      }
    }
  }
}

// ---------------------------------------------------------------------------
// Persistent GRU recurrence: 64 autonomous waves (64 WGs x 64 thr), proven
// sc0 sc1 LLC exchange (R6) + CANARY pre-gate:
//  - producers: 4 tagged data stores (step tag mod 4 in f16 bit0), then
//    canary[rk] = t+1 (same sc0sc1 path, no drain)
//  - consumers: spin on 32 canaries (1 dword/lane) until all >= t, THEN one
//    16KB bulk load + per-dword tag validation (correctness guard vs store
//    reordering; rare re-load). Cuts repeated bulk-retry LLC traffic.
//  - retry budget -> diagnosable fast-fail, never a hang
// ---------------------------------------------------------------------------
#define TS 1024

__global__ __launch_bounds__(64, 1) void gru_kernel(
    const float* __restrict__ w_hh, const float* __restrict__ b_hh,
    const u16* __restrict__ wx, u16* __restrict__ hs,
    u32* __restrict__ canary, u16* __restrict__ hbuf) {
  const int lane = threadIdx.x & 63;
  const int rk = blockIdx.x;              // 0..63
  const int wgq = rk >> 2;                // h-col quad 0..15 (K-block)
  const int mt = (rk >> 1) & 1;           // seq half
  const int jblk = rk & 1;                // 16-col half within the quad
  const int colL = jblk * 16 + (lane & 15);
  const int colH = wgq * 32 + colL;
  const int k0 = (lane >> 4) << 3;
  const int seqb = mt * 16 + ((lane >> 4) << 2);

  // ---- weights f16, register-resident: 3 gates x 16 k-blocks
  half8 wf[3][16];
#pragma unroll
  for (int g = 0; g < 3; ++g) {
    const float* wrow = w_hh + (size_t)(g * 512 + colH) * 512 + k0;
#pragma unroll
    for (int kb = 0; kb < 16; ++kb) {
      half8 v;
#pragma unroll
      for (int e = 0; e < 8; ++e) v[e] = (_Float16)wrow[kb * 32 + e];
      wf[g][kb] = v;
    }
  }
  const float bR = b_hh[colH], bZ = b_hh[512 + colH], bN = b_hh[1024 + colH];

  // probe voffsets (bytes)
  u32 pvoff[16];
#pragma unroll
  for (int kb = 0; kb < 16; ++kb) pvoff[kb] = (u32)(((kb * 2 + mt) * 64 + lane) * 16);
  const u32 svoff0 =
      (u32)((((wgq * 2 + mt) * 64 +
              (((lane >> 4) << 2) | (((colL >> 3) & 3) << 4))) * 8 + (lane & 7)) * 2);
  // canary: this wave's slot (64B stride); source slot for the spin loop
  const u32 cvoff_me = (u32)(rk * 64);
  const int srk = ((lane & 31) >> 1) * 4 + mt * 2 + (lane & 1);  // 32 sources
  const u32 cvoff_src = (u32)(srk * 64);
  const u64 cb = (u64)canary;

  // wx(0) prefetch
  u16 wxr[3][4];
#pragma unroll
  for (int g = 0; g < 3; ++g)
#pragma unroll
    for (int r = 0; r < 4; ++r)
      wxr[g][r] = wx[(size_t)(seqb + r) * 1536 + g * 512 + colH];

  float h_old[4] = {0.f, 0.f, 0.f, 0.f};
  int budget = 2000000;  // bounded-retry guard (fast-fail, never hang)

  for (int t = 0; t < TS; ++t) {
    f32x4 accS[3];
    if (t > 0) {
      // ---- canary pre-gate: wait until all 32 sources report step >= t
      for (;;) {
        u32 cv;
        asm volatile("global_load_dword %0, %1, %2 sc0 sc1\n\ts_waitcnt vmcnt(0)"
                     : "=v"(cv) : "v"(cvoff_src), "s"(cb) : "memory");
        if (__all((int)(cv >= (u32)t))) break;
        if (--budget < 0) break;
      }
      // ---- bulk load + tag validation (usually single pass)
      const u64 sb = (u64)(hbuf + ((t - 1) & 1) * 16384);
      const u32 p = (u32)((t - 1) & 1) | ((u32)(((t - 1) >> 1) & 1) << 16);
      u32x4 f[16];
      for (;;) {
#pragma unroll
        for (int kb = 0; kb < 16; ++kb)
          asm volatile("global_load_dwordx4 %0, %1, %2 sc0 sc1"
                       : "=v"(f[kb]) : "v"(pvoff[kb]), "s"(sb) : "memory");
        asm volatile("s_waitcnt vmcnt(0)" ::: "memory");
        __builtin_amdgcn_sched_barrier(0);
        u32 aOR = 0u, aAND = 0xFFFFFFFFu;
#pragma unroll
        for (int kb = 0; kb < 16; ++kb)
#pragma unroll
          for (int d = 0; d < 4; ++d) { aOR |= f[kb][d]; aAND &= f[kb][d]; }
        int ok = ((aOR & 0x00010001u) == p) & ((aAND & 0x00010001u) == p);
        if (__all(ok)) break;
        if (--budget < 0) break;
      }
      f32x4 a[3][2];
#pragma unroll
      for (int g = 0; g < 3; ++g) {
        a[g][0] = (f32x4){0.f, 0.f, 0.f, 0.f};
        a[g][1] = (f32x4){0.f, 0.f, 0.f, 0.f};
      }
#pragma unroll
      for (int kb = 0; kb < 16; kb += 2) {
        half8 h0 = as_h8u(f[kb]), h1 = as_h8u(f[kb + 1]);
#pragma unroll
        for (int g = 0; g < 3; ++g) {
          a[g][0] = __builtin_amdgcn_mfma_f32_16x16x32_f16(h0, wf[g][kb], a[g][0], 0, 0, 0);
          a[g][1] = __builtin_amdgcn_mfma_f32_16x16x32_f16(h1, wf[g][kb + 1], a[g][1], 0, 0, 0);
        }
      }
#pragma unroll
      for (int g = 0; g < 3; ++g) accS[g] = a[g][0] + a[g][1];
    } else {
#pragma unroll
      for (int g = 0; g < 3; ++g) accS[g] = (f32x4){0.f, 0.f, 0.f, 0.f};
    }

    // prefetch wx(t+1) (off critical path)
    u16 wxn[3][4];
    {
      int tp = (t + 1 < TS) ? t + 1 : t;
#pragma unroll
      for (int g = 0; g < 3; ++g)
#pragma unroll
        for (int r = 0; r < 4; ++r)
          wxn[g][r] = wx[(size_t)(tp * 32 + seqb + r) * 1536 + g * 512 + colH];
    }

    // gates in registers; tagged h stores (sc0 sc1 -> LLC) issue ASAP
    const u64 sb2 = (u64)(hbuf + (t & 1) * 16384);
    const u32 tagbit = (colL & 1) ? (u32)((t >> 1) & 1) : (u32)(t & 1);
    u32 hbits_s[4];
#pragma unroll
    for (int r = 0; r < 4; ++r) {
      float pr = h2f(wxr[0][r]) + accS[0][r] + bR;
      float pz = h2f(wxr[1][r]) + accS[1][r] + bZ;
      float rr = __builtin_amdgcn_rcpf(1.f + __expf(-pr));
      float zz = __builtin_amdgcn_rcpf(1.f + __expf(-pz));
      float xx = h2f(wxr[2][r]) + rr * (accS[2][r] + bN);
      float nn = 1.f - 2.f * __builtin_amdgcn_rcpf(__expf(2.f * xx) + 1.f);
      float hv = (1.f - zz) * nn + zz * h_old[r];
      h_old[r] = hv;
      u32 hbits = (u32)f2h(hv);
      hbits_s[r] = hbits;
      u32 tv = (hbits & 0xFFFEu) | tagbit;
      asm volatile("global_store_short %0, %1, %2 sc0 sc1"
                   :: "v"(svoff0 + r * 16), "v"(tv), "s"(sb2) : "memory");
    }
    // canary AFTER data stores (no drain; tags guard the race)
    if (lane == 0) {
      u32 cv = (u32)(t + 1);
      asm volatile("global_store_dword %0, %1, %2 sc0 sc1"
                   :: "v"(cvoff_me), "v"(cv), "s"(cb) : "memory");
    }
    // exact (untagged) copy to the output path, off the recurrence
#pragma unroll
    for (int r = 0; r < 4; ++r)
      hs[((size_t)((seqb + r) * TS + t) << 9) + colH] = (u16)hbits_s[r];
#pragma unroll
    for (int g = 0; g < 3; ++g)
#pragma unroll
      for (int r = 0; r < 4; ++r) wxr[g][r] = wxn[g][r];
  }
}

// ---------------------------------------------------------------------------
extern "C" void kernel_launch(void* const* d_in, const int* in_sizes, int n_in,
                              void* d_out, int out_size, void* d_ws, size_t ws_size,
                              hipStream_t stream) {
  const float* src = (const float*)d_in[0];   // [32,1024,256]
  const float* w_ih = (const float*)d_in[1];  // [1536,256]
  const float* w_hh = (const float*)d_in[2];  // [1536,512]
  const float* b_ih = (const float*)d_in[3];  // [1536]
  const float* b_hh = (const float*)d_in[4];  // [1536]
  const float* regw = (const float*)d_in[5];  // [256,512]
  const float* regb = (const float*)d_in[6];  // [256]

  char* ws = (char*)d_ws;
  u16* wx = (u16*)(ws);                  // [t][seq][1536] f16 = 100663296 B
  u16* hs = (u16*)(ws + 100663296LL);    // [seq*1024+t][512] f16 = 33554432 B
  u16* wihb = (u16*)(ws + 134217728LL);  // 1536x256 f16 (dead after wx GEMM)
  u16* rwb = (u16*)(ws + 135004160LL);   // 256x512 f16
  // canary + hbuf reuse the dead wihb region during gru:
  u32* canary = (u32*)(ws + 134217728LL);       // 64 x 64B = 4 KB
  u16* hbuf = (u16*)(ws + 134217728LL + 4096);  // 2 x 32 KB frag double-buffer

  cvt16<<<384, 256, 0, stream>>>(w_ih, wihb, 393216);
  cvt16<<<128, 256, 0, stream>>>(regw, rwb, 131072);

  {  // wx = src @ w_ih^T + b_ih, stored remapped [t][seq][1536] (f16)
    dim3 g(256, 12);
    gemm_kernel<true, false, true><<<g, 512, 0, stream>>>(
        (const void*)src, wihb, b_ih, (void*)wx, 32768, 1536, 256);
  }
  // re-init per launch AFTER the wx GEMM consumed wihb (stream-ordered):
  hipMemsetAsync(ws + 134217728LL, 0, 4096, stream);              // canary = 0
  hipMemsetAsync(ws + 134217728LL + 4096, 0xFF, 65536, stream);   // hbuf tags stale
  gru_kernel<<<64, 64, 0, stream>>>(w_hh, b_hh, wx, hs, canary, hbuf);
  {  // out = hs @ reg_w^T + reg_b  (f32 out)
    dim3 g(256, 2);
    gemm_kernel<false, true, false><<<g, 512, 0, stream>>>(
        (const void*)hs, rwb, regb, d_out, 32768, 256, 512);
  }
}

// Round 11
// 2175.104 us; speedup vs baseline: 3.5203x; 1.0648x over previous
//
#include <hip/hip_runtime.h>
#include <hip/hip_bf16.h>

typedef unsigned short u16;
typedef unsigned int u32;
typedef unsigned long long u64;
typedef __attribute__((ext_vector_type(8))) short short8;
typedef __attribute__((ext_vector_type(4))) unsigned int u32x4;
typedef __attribute__((ext_vector_type(4))) float f32x4;
typedef __attribute__((ext_vector_type(8))) _Float16 half8;

__device__ __forceinline__ u16 f2h(float f) {
  _Float16 h = (_Float16)f;
  u16 r;
  __builtin_memcpy(&r, &h, 2);
  return r;
}
__device__ __forceinline__ float h2f(u16 b) {
  _Float16 h;
  __builtin_memcpy(&h, &b, 2);
  return (float)h;
}
__device__ __forceinline__ half8 as_h8(short8 s) {
  half8 h;
  __builtin_memcpy(&h, &s, 16);
  return h;
}
__device__ __forceinline__ half8 as_h8u(u32x4 s) {
  half8 h;
  __builtin_memcpy(&h, &s, 16);
  return h;
}

// f32 -> f16 convert (4 elems/thread)
__global__ void cvt16(const float* __restrict__ in, u16* __restrict__ out, int n) {
  int i = (blockIdx.x * blockDim.x + threadIdx.x) * 4;
  if (i < n) {
    f32x4 v = *(const f32x4*)(in + i);
    out[i + 0] = f2h(v[0]);
    out[i + 1] = f2h(v[1]);
    out[i + 2] = f2h(v[2]);
    out[i + 3] = f2h(v[3]);
  }
}

// ---------------------------------------------------------------------------
// Tiled f16 MFMA GEMM:  C[M][N] = A[M][K] * B[N][K]^T + bias[N]
// BM=BN=128, BK=128, block=512. REMAP: store row m -> (m&1023)*32+(m>>10)
// ---------------------------------------------------------------------------
template <bool A_F32, bool OUT_F32, bool REMAP>
__global__ __launch_bounds__(512, 1) void gemm_kernel(
    const void* __restrict__ Ag, const u16* __restrict__ Bg,
    const float* __restrict__ bias, void* __restrict__ Cg,
    int M, int N, int K) {
  __shared__ __align__(16) u16 As[128 * 128];
  __shared__ __align__(16) u16 Bs[128 * 128];
  const int tid = threadIdx.x;
  const int lane = tid & 63, wave = tid >> 6;
  const int wm = wave & 1, wn = wave >> 1;
  const int m0 = blockIdx.x * 128, n0 = blockIdx.y * 128;

  f32x4 acc[4][2];
#pragma unroll
  for (int i = 0; i < 4; ++i) {
    acc[i][0] = (f32x4){0.f, 0.f, 0.f, 0.f};
    acc[i][1] = (f32x4){0.f, 0.f, 0.f, 0.f};
  }

  const int nk = K >> 7;
  for (int ks = 0; ks < nk; ++ks) {
    for (int i = tid; i < 128 * 16; i += 512) {
      int r = i >> 4, c = i & 15;
      int sw = c ^ (r & 7);
      short8 v;
      if (A_F32) {
        const float* ap = (const float*)Ag + (size_t)(m0 + r) * K + ks * 128 + c * 8;
#pragma unroll
        for (int e = 0; e < 8; ++e) v[e] = (short)f2h(ap[e]);
      } else {
        v = *(const short8*)((const u16*)Ag + (size_t)(m0 + r) * K + ks * 128 + c * 8);
      }
      *(short8*)(As + (r * 16 + sw) * 8) = v;
    }
    for (int i = tid; i < 128 * 16; i += 512) {
      int r = i >> 4, c = i & 15;
      int sw = c ^ (r & 7);
      *(short8*)(Bs + (r * 16 + sw) * 8) =
          *(const short8*)(Bg + (size_t)(n0 + r) * K + ks * 128 + c * 8);
    }
    __syncthreads();
#pragma unroll
    for (int kb = 0; kb < 4; ++kb) {
      const int cq = kb * 4 + (lane >> 4);
      short8 bfr[2];
#pragma unroll
      for (int j = 0; j < 2; ++j) {
        int rr = wn * 32 + j * 16 + (lane & 15);
        bfr[j] = *(const short8*)(Bs + (rr * 16 + (cq ^ (rr & 7))) * 8);
      }
#pragma unroll
      for (int i2 = 0; i2 < 4; ++i2) {
        int rr = wm * 64 + i2 * 16 + (lane & 15);
        short8 af = *(const short8*)(As + (rr * 16 + (cq ^ (rr & 7))) * 8);
        acc[i2][0] = __builtin_amdgcn_mfma_f32_16x16x32_f16(as_h8(af), as_h8(bfr[0]),
                                                            acc[i2][0], 0, 0, 0);
        acc[i2][1] = __builtin_amdgcn_mfma_f32_16x16x32_f16(as_h8(af), as_h8(bfr[1]),
                                                            acc[i2][1], 0, 0, 0);
      }
    }
    __syncthreads();
  }
#pragma unroll
  for (int i2 = 0; i2 < 4; ++i2) {
#pragma unroll
    for (int j = 0; j < 2; ++j) {
      int ncol = n0 + wn * 32 + j * 16 + (lane & 15);
      float bv = bias[ncol];
#pragma unroll
      for (int r2 = 0; r2 < 4; ++r2) {
        int mrow = m0 + wm * 64 + i2 * 16 + ((lane >> 4) << 2) + r2;
        size_t orow = REMAP ? ((size_t)(mrow & 1023) * 32 + (mrow >> 10)) : (size_t)mrow;
        float v = acc[i2][j][r2] + bv;
        if (OUT_F32)
          ((float*)Cg)[orow * N + ncol] = v;
        else
          ((u16*)Cg)[orow * N + ncol] = f2h(v);
      }
    }
  }
}

// ---------------------------------------------------------------------------
// Persistent GRU recurrence: 64 fully-AUTONOMOUS waves (64 WGs x 64 thr).
// Sync protocol IDENTICAL to the proven R6 kernel (tag-validate-retry on
// sc0 sc1 LLC exchange, 2-bit step tags in f16 bit0, fire-and-forget stores).
// Placement-only changes vs R6:
//  - hs[t-1] written EARLY in step t from h_old registers (bit-identical
//    values) so the HBM store ack hides under MFMA+gates instead of
//    serializing into the next step's vmcnt(0) drain
//  - wx(t+1) prefetch issued right after validation (before MFMA) so its
//    completion wait is off the critical path
// ---------------------------------------------------------------------------
#define TS 1024

__global__ __launch_bounds__(64, 1) void gru_kernel(
    const float* __restrict__ w_hh, const float* __restrict__ b_hh,
    const u16* __restrict__ wx, u16* __restrict__ hs,
    u16* __restrict__ hbuf) {
  const int lane = threadIdx.x & 63;
  const int wgq = blockIdx.x >> 2;        // h-col quad 0..15 (K-block kb)
  const int mt = (blockIdx.x >> 1) & 1;   // seq half
  const int jblk = blockIdx.x & 1;        // 16-col half within the quad
  const int colL = jblk * 16 + (lane & 15);  // col local 0..31
  const int colH = wgq * 32 + colL;          // global h col
  const int k0 = (lane >> 4) << 3;
  const int seqb = mt * 16 + ((lane >> 4) << 2);  // base seq for r=0

  // ---- weights f16, register-resident: 3 gates x 16 k-blocks
  half8 wf[3][16];
#pragma unroll
  for (int g = 0; g < 3; ++g) {
    const float* wrow = w_hh + (size_t)(g * 512 + colH) * 512 + k0;
#pragma unroll
    for (int kb = 0; kb < 16; ++kb) {
      half8 v;
#pragma unroll
      for (int e = 0; e < 8; ++e) v[e] = (_Float16)wrow[kb * 32 + e];
      wf[g][kb] = v;
    }
  }
  const float bR = b_hh[colH], bZ = b_hh[512 + colH], bN = b_hh[1024 + colH];

  // probe voffsets (bytes): consumer A-frag dwordx4 at ((kb*2+mt)*64+lane)*16
  u32 pvoff[16];
#pragma unroll
  for (int kb = 0; kb < 16; ++kb) pvoff[kb] = (u32)(((kb * 2 + mt) * 64 + lane) * 16);
  // store voffset (bytes) for r=0; r adds 16B (lane_c increments by 1)
  const u32 svoff0 =
      (u32)((((wgq * 2 + mt) * 64 +
              (((lane >> 4) << 2) | (((colL >> 3) & 3) << 4))) * 8 + (lane & 7)) * 2);

  // wx(0) prefetch (12 u16 per lane)
  u16 wxr[3][4];
#pragma unroll
  for (int g = 0; g < 3; ++g)
#pragma unroll
    for (int r = 0; r < 4; ++r)
      wxr[g][r] = wx[(size_t)(seqb + r) * 1536 + g * 512 + colH];

  float h_old[4] = {0.f, 0.f, 0.f, 0.f};
  int budget = 4000000;  // bounded-retry guard (fast-fail, never hang)

  for (int t = 0; t < TS; ++t) {
    f32x4 accS[3];
    u16 wxn[3][4];
    if (t > 0) {
      const u64 sb = (u64)(hbuf + ((t - 1) & 1) * 16384);
      const u32 p = (u32)((t - 1) & 1) | ((u32)(((t - 1) >> 1) & 1) << 16);
      u32x4 f[16];
      // validate-retry: data is fresh iff every dword carries tag (t-1)&3
      for (;;) {
#pragma unroll
        for (int kb = 0; kb < 16; ++kb)
          asm volatile("global_load_dwordx4 %0, %1, %2 sc0 sc1"
                       : "=v"(f[kb]) : "v"(pvoff[kb]), "s"(sb) : "memory");
        asm volatile("s_waitcnt vmcnt(0)" ::: "memory");
        __builtin_amdgcn_sched_barrier(0);
        u32 aOR = 0u, aAND = 0xFFFFFFFFu;
#pragma unroll
        for (int kb = 0; kb < 16; ++kb)
#pragma unroll
          for (int d = 0; d < 4; ++d) { aOR |= f[kb][d]; aAND &= f[kb][d]; }
        int ok = ((aOR & 0x00010001u) == p) & ((aAND & 0x00010001u) == p);
        if (__all(ok)) break;
        if (--budget < 0) break;  // diagnosable fast-fail, no timeout
      }
      // ---- EARLY hs write of h(t-1) from registers (bit-identical to the
      //      values exchanged last step); HBM ack hides under MFMA+gates
#pragma unroll
      for (int r = 0; r < 4; ++r)
        hs[((size_t)((seqb + r) * TS + (t - 1)) << 9) + colH] = f2h(h_old[r]);
      // ---- wx(t+1) prefetch issued before MFMA (completion off critical path)
      {
        int tp = (t + 1 < TS) ? t + 1 : t;
#pragma unroll
        for (int g = 0; g < 3; ++g)
#pragma unroll
          for (int r = 0; r < 4; ++r)
            wxn[g][r] = wx[(size_t)(tp * 32 + seqb + r) * 1536 + g * 512 + colH];
      }
      f32x4 a[3][2];
#pragma unroll
      for (int g = 0; g < 3; ++g) {
        a[g][0] = (f32x4){0.f, 0.f, 0.f, 0.f};
        a[g][1] = (f32x4){0.f, 0.f, 0.f, 0.f};
      }
#pragma unroll
      for (int kb = 0; kb < 16; kb += 2) {
        half8 h0 = as_h8u(f[kb]), h1 = as_h8u(f[kb + 1]);
#pragma unroll
        for (int g = 0; g < 3; ++g) {
          a[g][0] = __builtin_amdgcn_mfma_f32_16x16x32_f16(h0, wf[g][kb], a[g][0], 0, 0, 0);
          a[g][1] = __builtin_amdgcn_mfma_f32_16x16x32_f16(h1, wf[g][kb + 1], a[g][1], 0, 0, 0);
        }
      }
#pragma unroll
      for (int g = 0; g < 3; ++g) accS[g] = a[g][0] + a[g][1];
    } else {
#pragma unroll
      for (int g = 0; g < 3; ++g) accS[g] = (f32x4){0.f, 0.f, 0.f, 0.f};
#pragma unroll
      for (int g = 0; g < 3; ++g)
#pragma unroll
        for (int r = 0; r < 4; ++r)
          wxn[g][r] = wx[(size_t)(1 * 32 + seqb + r) * 1536 + g * 512 + colH];
    }

    // gates in registers; tagged h store issues per-r ASAP
    const u64 sb2 = (u64)(hbuf + (t & 1) * 16384);
    const u32 tagbit = (colL & 1) ? (u32)((t >> 1) & 1) : (u32)(t & 1);
#pragma unroll
    for (int r = 0; r < 4; ++r) {
      float pr = h2f(wxr[0][r]) + accS[0][r] + bR;
      float pz = h2f(wxr[1][r]) + accS[1][r] + bZ;
      float rr = __builtin_amdgcn_rcpf(1.f + __expf(-pr));
      float zz = __builtin_amdgcn_rcpf(1.f + __expf(-pz));
      float xx = h2f(wxr[2][r]) + rr * (accS[2][r] + bN);
      float nn = 1.f - 2.f * __builtin_amdgcn_rcpf(__expf(2.f * xx) + 1.f);
      float hv = (1.f - zz) * nn + zz * h_old[r];
      h_old[r] = hv;
      u32 hbits = (u32)f2h(hv);
      u32 tv = (hbits & 0xFFFEu) | tagbit;
      asm volatile("global_store_short %0, %1, %2 sc0 sc1"
                   :: "v"(svoff0 + r * 16), "v"(tv), "s"(sb2) : "memory");
      if (t == TS - 1)  // final step: no step t+1 exists to write hs[1023]
        hs[((size_t)((seqb + r) * TS + t) << 9) + colH] = (u16)hbits;
    }
#pragma unroll
    for (int g = 0; g < 3; ++g)
#pragma unroll
      for (int r = 0; r < 4; ++r) wxr[g][r] = wxn[g][r];
  }
}

// ---------------------------------------------------------------------------
extern "C" void kernel_launch(void* const* d_in, const int* in_sizes, int n_in,
                              void* d_out, int out_size, void* d_ws, size_t ws_size,
                              hipStream_t stream) {
  const float* src = (const float*)d_in[0];   // [32,1024,256]
  const float* w_ih = (const float*)d_in[1];  // [1536,256]
  const float* w_hh = (const float*)d_in[2];  // [1536,512]
  const float* b_ih = (const float*)d_in[3];  // [1536]
  const float* b_hh = (const float*)d_in[4];  // [1536]
  const float* regw = (const float*)d_in[5];  // [256,512]
  const float* regb = (const float*)d_in[6];  // [256]

  char* ws = (char*)d_ws;
  u16* wx = (u16*)(ws);                  // [t][seq][1536] f16 = 100663296 B
  u16* hs = (u16*)(ws + 100663296LL);    // [seq*1024+t][512] f16 = 33554432 B
  u16* wihb = (u16*)(ws + 134217728LL);  // 1536x256 f16 (dead after wx GEMM)
  u16* rwb = (u16*)(ws + 135004160LL);   // 256x512 f16
  // hbuf reuses the dead wihb region during gru:
  u16* hbuf = (u16*)(ws + 134217728LL + 4096);  // 2 x 32 KB frag double-buffer

  cvt16<<<384, 256, 0, stream>>>(w_ih, wihb, 393216);
  cvt16<<<128, 256, 0, stream>>>(regw, rwb, 131072);

  {  // wx = src @ w_ih^T + b_ih, stored remapped [t][seq][1536] (f16)
    dim3 g(256, 12);
    gemm_kernel<true, false, true><<<g, 512, 0, stream>>>(
        (const void*)src, wihb, b_ih, (void*)wx, 32768, 1536, 256);
  }
  // init hbuf to 0xFF AFTER the wx GEMM consumed wihb: tag bits (1,1) mismatch
  // t=1/t=2 expectations; also kills the 0xAA-poison (tag 0) collision.
  hipMemsetAsync(ws + 134217728LL + 4096, 0xFF, 65536, stream);
  gru_kernel<<<64, 64, 0, stream>>>(w_hh, b_hh, wx, hs, hbuf);
  {  // out = hs @ reg_w^T + reg_b  (f32 out)
    dim3 g(256, 2);
    gemm_kernel<false, true, false><<<g, 512, 0, stream>>>(
        (const void*)hs, rwb, regb, d_out, 32768, 256, 512);
  }
}